// Round 15
// baseline (525.730 us; speedup 1.0000x reference)
//
#include <hip/hip_runtime.h>
#include <hip/hip_bf16.h>
#include <hip/hip_cooperative_groups.h>

namespace cg = cooperative_groups;

#define N_NODES 16384
#define N_EDGES 65536
#define NB      32
#define H       64
#define NLAYERS 3
#define NEG     0.1f
#define LN_EPS  1e-5f

typedef _Float16 f16;
typedef _Float16 f16x2 __attribute__((ext_vector_type(2)));
typedef _Float16 f16x8 __attribute__((ext_vector_type(8)));
typedef __fp16   hf16x2 __attribute__((ext_vector_type(2)));
typedef float    f32x16 __attribute__((ext_vector_type(16)));

union F16x8 { f16x8 v; f16x2 p[4]; int4 i4; int2 i2[2]; };
union F16x2U { f16x2 h2; hf16x2 raw; unsigned int u; };
union F16U   { f16 h; unsigned short u; };

__device__ __forceinline__ f16x2 pkrtz(float a, float b) {
    F16x2U t; t.raw = __builtin_amdgcn_cvt_pkrtz(a, b); return t.h2;
}
__device__ __forceinline__ float leaky(float v) { return v > 0.f ? v : NEG * v; }

#define HS_STRIDE 76   // u16; 152 B rows -> 2-way LDS banks (free)

// ================================================================ shared helpers
__device__ __forceinline__ void loadB8(const f16* __restrict__ Bp, int c, int oq, int lane, F16x8* dstB) {
    const f16* base = Bp + (((size_t)(c * 16 + oq)) << 9) + lane * 8;
#pragma unroll
    for (int di = 0; di < 2; di++)
#pragma unroll
        for (int ks = 0; ks < 4; ks++)
            dstB[di * 4 + ks].i4 = *(const int4*)(base + ((di * 8 + ks * 2) << 9));
}
__device__ __forceinline__ void loadB4(const f16* __restrict__ Bp, int oq, int lane, F16x8* dstB) {
    const f16* base = Bp + (((size_t)(512 + oq)) << 9) + lane * 8;
#pragma unroll
    for (int ks = 0; ks < 4; ks++)
        dstB[ks].i4 = *(const int4*)(base + ((ks * 2) << 9));
}
__device__ __forceinline__ void msg_chunk2(int c, const F16x8* __restrict__ B,
                                           const unsigned short* hp0,
                                           const unsigned short* hp1,
                                           const f16x2 (*e2p)[4][4], f32x16* CC) {
    unsigned int rr0 = *(const unsigned int*)(hp0 + 2 * c);
    unsigned int rr1 = *(const unsigned int*)(hp1 + 2 * c);
    F16x2U h00, h01, h10, h11;
    h00.u = __builtin_amdgcn_perm(rr0, rr0, 0x01000100u);
    h10.u = __builtin_amdgcn_perm(rr0, rr0, 0x03020302u);
    h01.u = __builtin_amdgcn_perm(rr1, rr1, 0x01000100u);
    h11.u = __builtin_amdgcn_perm(rr1, rr1, 0x03020302u);
#pragma unroll
    for (int ks = 0; ks < 4; ks++) {
        F16x8 A00, A01, A10, A11;
#pragma unroll
        for (int r = 0; r < 4; r++) {
            A00.p[r] = h00.h2 * e2p[0][ks][r];
            A01.p[r] = h01.h2 * e2p[1][ks][r];
            A10.p[r] = h10.h2 * e2p[0][ks][r];
            A11.p[r] = h11.h2 * e2p[1][ks][r];
        }
        CC[0] = __builtin_amdgcn_mfma_f32_32x32x16_f16(A00.v, B[0 * 4 + ks].v, CC[0], 0, 0, 0);
        CC[1] = __builtin_amdgcn_mfma_f32_32x32x16_f16(A01.v, B[0 * 4 + ks].v, CC[1], 0, 0, 0);
        CC[2] = __builtin_amdgcn_mfma_f32_32x32x16_f16(A10.v, B[1 * 4 + ks].v, CC[2], 0, 0, 0);
        CC[3] = __builtin_amdgcn_mfma_f32_32x32x16_f16(A11.v, B[1 * 4 + ks].v, CC[3], 0, 0, 0);
    }
}
// r7 ring helpers (harness-verified at 512thr/256blk, 92 VGPR)
__device__ __forceinline__ void stageChunk(const f16* __restrict__ Bp, int c, f16* ring, int w, int lane) {
    const f16* g = Bp + (((size_t)(c * 16 + w * 2)) << 9) + lane * 8;
    f16* l = ring + (c % 3) * 8192 + ((w * 2) << 9);
#pragma unroll
    for (int s = 0; s < 2; s++)
        __builtin_amdgcn_global_load_lds(
            (const __attribute__((address_space(1))) unsigned int*)(g + (s << 9)),
            (__attribute__((address_space(3))) unsigned int*)(l + (s << 9)), 16, 0, 0);
}
__device__ __forceinline__ void readBr(const f16* rslot, int oq, int lane, F16x8* Bf) {
#pragma unroll
    for (int di = 0; di < 2; di++)
#pragma unroll
        for (int ks = 0; ks < 4; ks++)
            Bf[di * 4 + ks].i4 = *(const int4*)(rslot + ((di * 8 + ks * 2 + oq) << 9) + lane * 8);
}

// ================================================================ LDS overlay for fused kernel
struct MsgSh7 {
    unsigned short hsL[256 * HS_STRIDE];  // 38912 B
    unsigned short eL[256 * 72];          // 36864 B (e1 then e2)
    f16 ring[3 * 8192];                   // 49152 B
    int dstL[256];                        // 1024 B
};                                        // 125952 B total
struct NodeSh { unsigned short hA[64 * 72]; float outL[64][68]; };
struct HeadSh { float cntL[32]; float ps[32][64]; float p1[32][64]; float p2[32][32]; };
union ShU { MsgSh7 m; NodeSh n; HeadSh hd; };   // max 125952 -> 1 block/CU

// ================================================================ fused phases
// ---- msg phase: r7's k_msg body verbatim (256 edges, 8 waves, LDS ring)
__device__ void msg_phase(MsgSh7& S,
                          const float* __restrict__ h, const float* __restrict__ ea,
                          const float* __restrict__ w1, const float* __restrict__ b1,
                          const float* __restrict__ w2, const float* __restrict__ b2,
                          const f16* __restrict__ Bp,
                          const int* __restrict__ src, const int* __restrict__ dst,
                          float* __restrict__ agg) {
    const int t    = threadIdx.x;
    const int lane = t & 63;
    const int w    = t >> 6;
    const int eh   = w >> 1, oq = w & 1;
    const int m    = lane & 31;
    const int kp   = lane >> 5;
    const int eb   = blockIdx.x * 256;

    stageChunk(Bp, 0, S.ring, w, lane);
    stageChunk(Bp, 1, S.ring, w, lane);

    {
        int e    = t >> 1;
        int half = t & 1;
        int nsrc = src[eb + e];
        const float4* hr = (const float4*)(h + (size_t)nsrc * 64 + half * 32);
        unsigned int* hrow = (unsigned int*)S.hsL + e * (HS_STRIDE / 2) + half * 16;
#pragma unroll
        for (int q = 0; q < 8; q++) {
            float4 v = hr[q];
            F16x2U p0, p1;
            p0.raw = __builtin_amdgcn_cvt_pkrtz(v.x, v.y);
            p1.raw = __builtin_amdgcn_cvt_pkrtz(v.z, v.w);
            hrow[q * 2 + 0] = p0.u;
            hrow[q * 2 + 1] = p1.u;
        }
        if (t < 256) S.dstL[t] = dst[eb + t];
    }

    {
        int kk = t & 63;
        int eg = t >> 6;
        float w1r[5];
#pragma unroll
        for (int d = 0; d < 5; d++) w1r[d] = w1[kk * 5 + d];
        float b1r = b1[kk];
        const float* ear = ea + (size_t)(eb + eg * 32) * 5;
#pragma unroll 4
        for (int g = 0; g < 32; g++) {
            float a0 = ear[g * 5 + 0], a1 = ear[g * 5 + 1], a2 = ear[g * 5 + 2];
            float a3 = ear[g * 5 + 3], a4 = ear[g * 5 + 4];
            float v = b1r + a0 * w1r[0] + a1 * w1r[1] + a2 * w1r[2] + a3 * w1r[3] + a4 * w1r[4];
            F16U z; z.h = (f16)leaky(v);
            S.eL[(eg * 32 + g) * 72 + kk] = z.u;
        }
    }
    __syncthreads();

    {
        F16x8 W2f[4];
#pragma unroll
        for (int ks = 0; ks < 4; ks++) {
            const float* s = w2 + (size_t)(oq * 32 + m) * 64 + ks * 16 + kp * 8;
            float4 a = ((const float4*)s)[0];
            float4 b = ((const float4*)s)[1];
            W2f[ks].p[0] = pkrtz(a.x, a.y);
            W2f[ks].p[1] = pkrtz(a.z, a.w);
            W2f[ks].p[2] = pkrtz(b.x, b.y);
            W2f[ks].p[3] = pkrtz(b.z, b.w);
        }
        float b2r = b2[oq * 32 + m];
        F16x8 A8[8];
#pragma unroll
        for (int tt = 0; tt < 2; tt++)
#pragma unroll
            for (int ks = 0; ks < 4; ks++)
                A8[tt * 4 + ks].i4 = *(const int4*)(S.eL + (size_t)((eh * 2 + tt) * 32 + m) * 72 + ks * 16 + kp * 8);
        __syncthreads();   // all e1 reads landed -> safe to overwrite with e2
#pragma unroll
        for (int tt = 0; tt < 2; tt++) {
            f32x16 C2 = {0,0,0,0,0,0,0,0,0,0,0,0,0,0,0,0};
#pragma unroll
            for (int ks = 0; ks < 4; ks++)
                C2 = __builtin_amdgcn_mfma_f32_32x32x16_f16(A8[tt * 4 + ks].v, W2f[ks].v, C2, 0, 0, 0);
#pragma unroll
            for (int reg = 0; reg < 16; reg++) {
                int r = (reg & 3) + 8 * (reg >> 2) + 4 * kp;
                F16U z; z.h = (f16)leaky(C2[reg] + b2r);
                S.eL[((eh * 2 + tt) * 32 + r) * 72 + oq * 32 + m] = z.u;
            }
        }
    }
    __syncthreads();

    f16x2 e2p[2][4][4];
#pragma unroll
    for (int tt = 0; tt < 2; tt++) {
#pragma unroll
        for (int ks = 0; ks < 4; ks++) {
            F16x8 q;
            q.i4 = *(const int4*)(S.eL + (size_t)((eh * 2 + tt) * 32 + m) * 72 + ks * 16 + kp * 8);
            e2p[tt][ks][0] = q.p[0]; e2p[tt][ks][1] = q.p[1];
            e2p[tt][ks][2] = q.p[2]; e2p[tt][ks][3] = q.p[3];
        }
    }

    f32x16 CC[4];
#pragma unroll
    for (int q = 0; q < 4; q++)
#pragma unroll
        for (int r = 0; r < 16; r++) CC[q][r] = 0.f;

    const unsigned short* hp0 = S.hsL + ((eh * 2 + 0) * 32 + m) * HS_STRIDE;
    const unsigned short* hp1 = S.hsL + ((eh * 2 + 1) * 32 + m) * HS_STRIDE;

    F16x8 Bf[8];
#pragma unroll 1
    for (int c = 0; c < 30; c++) {
        asm volatile("s_waitcnt vmcnt(2)" ::: "memory");
        __builtin_amdgcn_s_barrier();
        stageChunk(Bp, c + 2, S.ring, w, lane);
        readBr(S.ring + (c % 3) * 8192, oq, lane, Bf);
        msg_chunk2(c, Bf, hp0, hp1, e2p, CC);
    }
    asm volatile("s_waitcnt vmcnt(2)" ::: "memory");
    __builtin_amdgcn_s_barrier();
    readBr(S.ring + (30 % 3) * 8192, oq, lane, Bf);
    msg_chunk2(30, Bf, hp0, hp1, e2p, CC);
    asm volatile("s_waitcnt vmcnt(0)" ::: "memory");
    __builtin_amdgcn_s_barrier();
    readBr(S.ring + (31 % 3) * 8192, oq, lane, Bf);
    F16x8 Bb[4];
    loadB4(Bp, oq, lane, Bb);
    msg_chunk2(31, Bf, hp0, hp1, e2p, CC);

#pragma unroll
    for (int ks = 0; ks < 4; ks++) {
        int koff = (ks * 16 + kp * 8) * 2;
        const char* r0p = (const char*)S.hsL + (size_t)((eh * 2 + 0) * 32 + m) * (HS_STRIDE * 2) + koff;
        const char* r1p = (const char*)S.hsL + (size_t)((eh * 2 + 1) * 32 + m) * (HS_STRIDE * 2) + koff;
        F16x8 A0, A1;
        A0.i2[0] = *(const int2*)(r0p); A0.i2[1] = *(const int2*)(r0p + 8);
        A1.i2[0] = *(const int2*)(r1p); A1.i2[1] = *(const int2*)(r1p + 8);
        CC[0] = __builtin_amdgcn_mfma_f32_32x32x16_f16(A0.v, Bb[ks].v, CC[0], 0, 0, 0);
        CC[1] = __builtin_amdgcn_mfma_f32_32x32x16_f16(A1.v, Bb[ks].v, CC[1], 0, 0, 0);
    }

    int o = oq * 32 + m;
#pragma unroll
    for (int reg = 0; reg < 16; reg++) {
        int r = (reg & 3) + 8 * (reg >> 2) + 4 * kp;
        atomicAdd(&agg[(size_t)S.dstL[(eh * 2 + 0) * 32 + r] * 64 + o], CC[0][reg] + CC[2][reg]);
    }
#pragma unroll
    for (int reg = 0; reg < 16; reg++) {
        int r = (reg & 3) + 8 * (reg >> 2) + 4 * kp;
        atomicAdd(&agg[(size_t)S.dstL[(eh * 2 + 1) * 32 + r] * 64 + o], CC[1][reg] + CC[3][reg]);
    }
}

// ---- node phase: r14's 512-thread k_node body verbatim
__device__ void node_phase(NodeSh& N,
                           const float* __restrict__ agg, const float* __restrict__ deg,
                           const float* __restrict__ rw, const float* __restrict__ rb,
                           const float* __restrict__ lg, const float* __restrict__ lb,
                           float* __restrict__ h, const int* __restrict__ batch,
                           float* __restrict__ pooled, int last) {
    int t = threadIdx.x;
    int nb = blockIdx.x * 64;
    int lane = t & 63, w = t >> 6;
    int m = lane & 31, kp = lane >> 5;

    int node = t >> 3, c0 = (t & 7) * 8;
    size_t gb = (size_t)(nb + node) * 64 + c0;
    float4 ag0 = *(const float4*)(agg + gb);
    float4 ag1 = *(const float4*)(agg + gb + 4);
    float4 hp0 = *(const float4*)(h + gb);
    float4 hp1 = *(const float4*)(h + gb + 4);
    float  vdeg = fmaxf(deg[nb + node], 1.0f);
    float4 gv0 = *(const float4*)(lg + c0);
    float4 gv1 = *(const float4*)(lg + c0 + 4);
    float4 bv0 = *(const float4*)(lb + c0);
    float4 bv1 = *(const float4*)(lb + c0 + 4);

    {
        unsigned int* drow = (unsigned int*)N.hA + node * 36 + c0 / 2;
        F16x2U p0, p1, p2, p3;
        p0.raw = __builtin_amdgcn_cvt_pkrtz(hp0.x, hp0.y);
        p1.raw = __builtin_amdgcn_cvt_pkrtz(hp0.z, hp0.w);
        p2.raw = __builtin_amdgcn_cvt_pkrtz(hp1.x, hp1.y);
        p3.raw = __builtin_amdgcn_cvt_pkrtz(hp1.z, hp1.w);
        drow[0] = p0.u; drow[1] = p1.u; drow[2] = p2.u; drow[3] = p3.u;
    }
    F16x8 Bf[4];
    if (t < 256) {
        int oq = w & 1;
#pragma unroll
        for (int ks = 0; ks < 4; ks++) {
            const float* s = rw + (size_t)(oq * 32 + m) * 64 + ks * 16 + kp * 8;
            float4 a = ((const float4*)s)[0];
            float4 b = ((const float4*)s)[1];
            Bf[ks].p[0] = pkrtz(a.x, a.y);
            Bf[ks].p[1] = pkrtz(a.z, a.w);
            Bf[ks].p[2] = pkrtz(b.x, b.y);
            Bf[ks].p[3] = pkrtz(b.z, b.w);
        }
    }
    __syncthreads();

    if (t < 256) {
        int nq = w >> 1, oq = w & 1;
        f32x16 C = {0,0,0,0,0,0,0,0,0,0,0,0,0,0,0,0};
#pragma unroll
        for (int ks = 0; ks < 4; ks++) {
            F16x8 A;
            A.i4 = *(const int4*)(N.hA + (size_t)(nq * 32 + m) * 72 + ks * 16 + kp * 8);
            C = __builtin_amdgcn_mfma_f32_32x32x16_f16(A.v, Bf[ks].v, C, 0, 0, 0);
        }
        int o = oq * 32 + m;
        float rbv = rb[o];
#pragma unroll
        for (int reg = 0; reg < 16; reg++) {
            int r = (reg & 3) + 8 * (reg >> 2) + 4 * kp;
            N.outL[nq * 32 + r][o] = C[reg] + rbv;
        }
    }
    __syncthreads();

    {
        float v[8];
        v[0] = N.outL[node][c0 + 0] + ag0.x / vdeg;
        v[1] = N.outL[node][c0 + 1] + ag0.y / vdeg;
        v[2] = N.outL[node][c0 + 2] + ag0.z / vdeg;
        v[3] = N.outL[node][c0 + 3] + ag0.w / vdeg;
        v[4] = N.outL[node][c0 + 4] + ag1.x / vdeg;
        v[5] = N.outL[node][c0 + 5] + ag1.y / vdeg;
        v[6] = N.outL[node][c0 + 6] + ag1.z / vdeg;
        v[7] = N.outL[node][c0 + 7] + ag1.w / vdeg;
        float s = 0.f;
#pragma unroll
        for (int i = 0; i < 8; i++) s += v[i];
        s += __shfl_xor(s, 1);
        s += __shfl_xor(s, 2);
        s += __shfl_xor(s, 4);
        float mu = s * (1.f / 64.f);
        float vs = 0.f;
#pragma unroll
        for (int i = 0; i < 8; i++) { float d = v[i] - mu; vs += d * d; }
        vs += __shfl_xor(vs, 1);
        vs += __shfl_xor(vs, 2);
        vs += __shfl_xor(vs, 4);
        float rs = rsqrtf(vs * (1.f / 64.f) + LN_EPS);
        float gfv[8] = { gv0.x, gv0.y, gv0.z, gv0.w, gv1.x, gv1.y, gv1.z, gv1.w };
        float bfv[8] = { bv0.x, bv0.y, bv0.z, bv0.w, bv1.x, bv1.y, bv1.z, bv1.w };
        float hfv[8] = { hp0.x, hp0.y, hp0.z, hp0.w, hp1.x, hp1.y, hp1.z, hp1.w };
        float hn[8];
#pragma unroll
        for (int i = 0; i < 8; i++) {
            float ov = (v[i] - mu) * rs * gfv[i] + bfv[i];
            hn[i] = leaky(ov) + hfv[i];
        }
        float4 hw0, hw1;
        hw0.x = hn[0]; hw0.y = hn[1]; hw0.z = hn[2]; hw0.w = hn[3];
        hw1.x = hn[4]; hw1.y = hn[5]; hw1.z = hn[6]; hw1.w = hn[7];
        *(float4*)(h + gb)     = hw0;
        *(float4*)(h + gb + 4) = hw1;
#pragma unroll
        for (int i = 0; i < 8; i++) N.outL[node][c0 + i] = hn[i];
    }

    if (last) {
        __syncthreads();
        float accp = 0.f;
        int cur = batch[nb + w * 8];
        for (int q = 0; q < 8; q++) {
            int n = w * 8 + q;
            float hv = N.outL[n][lane];
            int b = batch[nb + n];
            if (b != cur) { atomicAdd(&pooled[cur * 64 + lane], accp); accp = 0.f; cur = b; }
            accp += hv;
        }
        atomicAdd(&pooled[cur * 64 + lane], accp);
    }
}

// ================================================================ fused cooperative kernel (r10 shell, proven launch+sync config)
__global__ __launch_bounds__(512) void k_fused(
    const float* __restrict__ x, const float* __restrict__ ea,
    const int* __restrict__ src, const int* __restrict__ dst, const int* __restrict__ bat,
    const float* __restrict__ Win, const float* __restrict__ bin,
    const float* __restrict__ ew1, const float* __restrict__ eb1,
    const float* __restrict__ ew2, const float* __restrict__ eb2,
    const float* __restrict__ ew3, const float* __restrict__ eb3,
    const float* __restrict__ rw, const float* __restrict__ rb,
    const float* __restrict__ lg, const float* __restrict__ lb,
    const float* __restrict__ pw1, const float* __restrict__ pb1,
    const float* __restrict__ pw2, const float* __restrict__ pb2,
    const float* __restrict__ pw3, const float* __restrict__ pb3,
    float* __restrict__ h, float* __restrict__ agg, float* __restrict__ deg,
    float* __restrict__ pooled, f16* __restrict__ Bp, float* __restrict__ out) {

    __shared__ __align__(16) ShU sh;
    cg::grid_group grid = cg::this_grid();

    const int t    = threadIdx.x;
    const int lane = t & 63;
    const int w    = t >> 6;

    // ---- setup phase (r10-proven)
    {
        int tg = blockIdx.x * 512 + t;
#pragma unroll
        for (int r = 0; r < 8; r++) {
            int idx = r * 131072 + tg;
            int n = idx >> 6, j = idx & 63;
            const float* xr = x + n * 4;
            const float* wr = Win + j * 4;
            float v = bin[j] + xr[0] * wr[0] + xr[1] * wr[1] + xr[2] * wr[2] + xr[3] * wr[3];
            h[idx] = leaky(v);
        }
        if (tg < N_EDGES) atomicAdd(&deg[dst[tg]], 1.0f);
        int wid = blockIdx.x * 8 + w;
        if (wid < 1560) {
            int l    = wid / 520;
            int slot = wid - l * 520;
            const float* ew3l = ew3 + (size_t)l * 262144;
            const float* eb3l = eb3 + (size_t)l * 4096;
            int i   = slot >> 3;
            int rem = slot & 7;
            int ks  = rem >> 1;
            int oq  = rem & 1;
            int o   = oq * 32 + (lane & 31);
            int k0  = ks * 16 + (lane >> 5) * 8;
            float v[8];
            if (i < 64) {
                const float* s = ew3l + ((size_t)(i * 64 + o)) * 64 + k0;
                float4 a = ((const float4*)s)[0];
                float4 b = ((const float4*)s)[1];
                v[0] = a.x; v[1] = a.y; v[2] = a.z; v[3] = a.w;
                v[4] = b.x; v[5] = b.y; v[6] = b.z; v[7] = b.w;
            } else {
#pragma unroll
                for (int j = 0; j < 8; j++) v[j] = eb3l[(k0 + j) * 64 + o];
            }
            union { int4 i4; f16 a[8]; } ov;
#pragma unroll
            for (int j = 0; j < 8; j++) ov.a[j] = (f16)v[j];
            *(int4*)(Bp + (size_t)l * 266240 + (size_t)slot * 512 + lane * 8) = ov.i4;
        }
    }
    grid.sync();

    for (int l = 0; l < NLAYERS; l++) {
        float* agg_l = agg + (size_t)l * N_NODES * H;
        msg_phase(sh.m, h, ea, ew1 + l * 320, eb1 + l * 64,
                  ew2 + l * 4096, eb2 + l * 64,
                  Bp + (size_t)l * 266240, src, dst, agg_l);
        grid.sync();
        node_phase(sh.n, agg_l, deg, rw + l * 4096, rb + l * 64,
                   lg + l * 64, lb + l * 64, h, bat, pooled,
                   l == NLAYERS - 1 ? 1 : 0);
        grid.sync();
    }

    // ---- head phase (r10-proven, block 0, 512 threads)
    if (blockIdx.x == 0) {
        HeadSh& Hh = sh.hd;
        if (t < 32) Hh.cntL[t] = 0.f;
        __syncthreads();
        {
            const int4* bp4 = (const int4*)(bat + t * 32);
            int cur = bat[t * 32];
            float c = 0.f;
            for (int q = 0; q < 8; q++) {
                int4 b4 = bp4[q];
                int bs[4] = { b4.x, b4.y, b4.z, b4.w };
#pragma unroll
                for (int e = 0; e < 4; e++) {
                    if (bs[e] != cur) { atomicAdd(&Hh.cntL[cur], c); cur = bs[e]; c = 0.f; }
                    c += 1.f;
                }
            }
            atomicAdd(&Hh.cntL[cur], c);
        }
        __syncthreads();
        for (int idx = t; idx < 2048; idx += 512) {
            int b = idx >> 6, j = idx & 63;
            Hh.ps[b][j] = pooled[idx] / fmaxf(Hh.cntL[b], 1.0f);
        }
        __syncthreads();
        for (int idx = t; idx < 2048; idx += 512) {
            int b = idx >> 6, j = idx & 63;
            float v = pb1[j];
#pragma unroll 8
            for (int i = 0; i < 64; i++) v += Hh.ps[b][i] * pw1[j * 64 + i];
            Hh.p1[b][j] = leaky(v);
        }
        __syncthreads();
        for (int idx = t; idx < 1024; idx += 512) {
            int b = idx >> 5, j = idx & 31;
            float v = pb2[j];
#pragma unroll 8
            for (int i = 0; i < 64; i++) v += Hh.p1[b][i] * pw2[j * 64 + i];
            Hh.p2[b][j] = leaky(v);
        }
        __syncthreads();
        if (t < 32) {
            float v = pb3[0];
#pragma unroll 8
            for (int i = 0; i < 32; i++) v += Hh.p2[t][i] * pw3[i];
            out[t] = v;
        }
    }
}

// ================================================================ FALLBACK: r14's verified kernel set (used if coop launch is rejected)
__global__ __launch_bounds__(256) void k_setup(const float* __restrict__ x,
                                               const float* __restrict__ Win,
                                               const float* __restrict__ bin,
                                               const int* __restrict__ dst,
                                               const float* __restrict__ ew3,
                                               const float* __restrict__ eb3,
                                               float* __restrict__ h,
                                               float* __restrict__ deg,
                                               f16* __restrict__ Bp) {
    int bid = blockIdx.x;
    if (bid < 4096) {
        int t = bid * 256 + threadIdx.x;
        int n = t >> 6, j = t & 63;
        const float* xr = x + n * 4;
        const float* wr = Win + j * 4;
        float v = bin[j] + xr[0] * wr[0] + xr[1] * wr[1] + xr[2] * wr[2] + xr[3] * wr[3];
        h[t] = leaky(v);
    } else if (bid < 4352) {
        int e = (bid - 4096) * 256 + threadIdx.x;
        atomicAdd(&deg[dst[e]], 1.0f);
    } else {
        int tg    = (bid - 4352) * 256 + threadIdx.x;
        int lane  = tg & 63;
        int gslot = tg >> 6;
        int l     = gslot / 520;
        int slot  = gslot - l * 520;
        const float* ew3l = ew3 + (size_t)l * 262144;
        const float* eb3l = eb3 + (size_t)l * 4096;
        int i   = slot >> 3;
        int rem = slot & 7;
        int ks  = rem >> 1;
        int oq  = rem & 1;
        int o   = oq * 32 + (lane & 31);
        int k0  = ks * 16 + (lane >> 5) * 8;
        float v[8];
        if (i < 64) {
            const float* s = ew3l + ((size_t)(i * 64 + o)) * 64 + k0;
            float4 a = ((const float4*)s)[0];
            float4 b = ((const float4*)s)[1];
            v[0] = a.x; v[1] = a.y; v[2] = a.z; v[3] = a.w;
            v[4] = b.x; v[5] = b.y; v[6] = b.z; v[7] = b.w;
        } else {
#pragma unroll
            for (int j = 0; j < 8; j++) v[j] = eb3l[(k0 + j) * 64 + o];
        }
        union { int4 i4; f16 a[8]; } outv;
#pragma unroll
        for (int j = 0; j < 8; j++) outv.a[j] = (f16)v[j];
        *(int4*)(Bp + (size_t)l * 266240 + (size_t)slot * 512 + lane * 8) = outv.i4;
    }
}

__global__ __launch_bounds__(256, 2) void k_msg(const float* __restrict__ h,
                                                const float* __restrict__ ea,
                                                const float* __restrict__ w1,
                                                const float* __restrict__ b1,
                                                const float* __restrict__ w2,
                                                const float* __restrict__ b2,
                                                const f16* __restrict__ Bp,
                                                const int* __restrict__ src,
                                                const int* __restrict__ dst,
                                                float* __restrict__ agg) {
    __shared__ __align__(16) unsigned short hsL[128 * HS_STRIDE];
    __shared__ __align__(16) unsigned short e1L[128 * 72];
    __shared__ __align__(16) unsigned short e2L[128 * 72];
    __shared__ float eas[128 * 8];
    __shared__ int dstL[128];

    const int t    = threadIdx.x;
    const int lane = t & 63;
    const int w    = t >> 6;
    const int eh   = w >> 1, oq = w & 1;
    const int m    = lane & 31;
    const int kp   = lane >> 5;
    const int eb   = blockIdx.x * 128;

    for (int idx = t; idx < 640; idx += 256) {
        int r = idx / 5, d = idx - r * 5;
        eas[r * 8 + d] = ea[(size_t)eb * 5 + idx];
    }
    {
        int e    = t >> 1;
        int half = t & 1;
        int nsrc = src[eb + e];
        const float4* hr = (const float4*)(h + (size_t)nsrc * 64 + half * 32);
        unsigned int* hrow = (unsigned int*)hsL + e * (HS_STRIDE / 2) + half * 16;
#pragma unroll
        for (int q = 0; q < 8; q++) {
            float4 v = hr[q];
            F16x2U p0, p1;
            p0.raw = __builtin_amdgcn_cvt_pkrtz(v.x, v.y);
            p1.raw = __builtin_amdgcn_cvt_pkrtz(v.z, v.w);
            hrow[q * 2 + 0] = p0.u;
            hrow[q * 2 + 1] = p1.u;
        }
        if (t < 128) dstL[t] = dst[eb + t];
    }
    __syncthreads();

    {
        int kk = t & 63;
        int eg = t >> 6;
        float w1r[5];
#pragma unroll
        for (int d = 0; d < 5; d++) w1r[d] = w1[kk * 5 + d];
        float b1r = b1[kk];
#pragma unroll 4
        for (int g = 0; g < 32; g++) {
            int row = eg * 32 + g;
            float4 a4 = *(const float4*)(eas + row * 8);
            float a5 = eas[row * 8 + 4];
            float v = b1r + a4.x * w1r[0] + a4.y * w1r[1] + a4.z * w1r[2] + a4.w * w1r[3] + a5 * w1r[4];
            F16U z; z.h = (f16)leaky(v);
            e1L[row * 72 + kk] = z.u;
        }
    }
    __syncthreads();

    {
        F16x8 W2f[4];
#pragma unroll
        for (int ks = 0; ks < 4; ks++) {
            const float* s = w2 + (size_t)(oq * 32 + m) * 64 + ks * 16 + kp * 8;
            float4 a = ((const float4*)s)[0];
            float4 b = ((const float4*)s)[1];
            W2f[ks].p[0] = pkrtz(a.x, a.y);
            W2f[ks].p[1] = pkrtz(a.z, a.w);
            W2f[ks].p[2] = pkrtz(b.x, b.y);
            W2f[ks].p[3] = pkrtz(b.z, b.w);
        }
        float b2r = b2[oq * 32 + m];
#pragma unroll
        for (int tt = 0; tt < 2; tt++) {
            f32x16 C2 = {0,0,0,0,0,0,0,0,0,0,0,0,0,0,0,0};
#pragma unroll
            for (int ks = 0; ks < 4; ks++) {
                F16x8 A;
                A.i4 = *(const int4*)(e1L + (size_t)((eh * 2 + tt) * 32 + m) * 72 + ks * 16 + kp * 8);
                C2 = __builtin_amdgcn_mfma_f32_32x32x16_f16(A.v, W2f[ks].v, C2, 0, 0, 0);
            }
#pragma unroll
            for (int reg = 0; reg < 16; reg++) {
                int r = (reg & 3) + 8 * (reg >> 2) + 4 * kp;
                F16U z; z.h = (f16)leaky(C2[reg] + b2r);
                e2L[((eh * 2 + tt) * 32 + r) * 72 + oq * 32 + m] = z.u;
            }
        }
    }
    __syncthreads();

    f16x2 e2p[2][4][4];
#pragma unroll
    for (int tt = 0; tt < 2; tt++) {
#pragma unroll
        for (int ks = 0; ks < 4; ks++) {
            F16x8 q;
            q.i4 = *(const int4*)(e2L + (size_t)((eh * 2 + tt) * 32 + m) * 72 + ks * 16 + kp * 8);
            e2p[tt][ks][0] = q.p[0]; e2p[tt][ks][1] = q.p[1];
            e2p[tt][ks][2] = q.p[2]; e2p[tt][ks][3] = q.p[3];
        }
    }

    f32x16 CC[4];
#pragma unroll
    for (int q = 0; q < 4; q++)
#pragma unroll
        for (int r = 0; r < 16; r++) CC[q][r] = 0.f;

    const unsigned short* hp0 = hsL + ((eh * 2 + 0) * 32 + m) * HS_STRIDE;
    const unsigned short* hp1 = hsL + ((eh * 2 + 1) * 32 + m) * HS_STRIDE;

    F16x8 B0[8], B1[8];
    loadB8(Bp, 0, oq, lane, B0);
    loadB8(Bp, 1, oq, lane, B1);
    for (int it = 0; it < 15; it++) {
        int c = it * 2;
        msg_chunk2(c,     B0, hp0, hp1, e2p, CC);  loadB8(Bp, c + 2, oq, lane, B0);
        msg_chunk2(c + 1, B1, hp0, hp1, e2p, CC);  loadB8(Bp, c + 3, oq, lane, B1);
    }
    msg_chunk2(30, B0, hp0, hp1, e2p, CC);
    loadB4(Bp, oq, lane, B0);
    msg_chunk2(31, B1, hp0, hp1, e2p, CC);

#pragma unroll
    for (int ks = 0; ks < 4; ks++) {
        int koff = (ks * 16 + kp * 8) * 2;
        const char* r0p = (const char*)hsL + (size_t)((eh * 2 + 0) * 32 + m) * (HS_STRIDE * 2) + koff;
        const char* r1p = (const char*)hsL + (size_t)((eh * 2 + 1) * 32 + m) * (HS_STRIDE * 2) + koff;
        F16x8 A0, A1;
        A0.i2[0] = *(const int2*)(r0p); A0.i2[1] = *(const int2*)(r0p + 8);
        A1.i2[0] = *(const int2*)(r1p); A1.i2[1] = *(const int2*)(r1p + 8);
        CC[0] = __builtin_amdgcn_mfma_f32_32x32x16_f16(A0.v, B0[ks].v, CC[0], 0, 0, 0);
        CC[1] = __builtin_amdgcn_mfma_f32_32x32x16_f16(A1.v, B0[ks].v, CC[1], 0, 0, 0);
    }

    int o = oq * 32 + m;
#pragma unroll
    for (int reg = 0; reg < 16; reg++) {
        int r = (reg & 3) + 8 * (reg >> 2) + 4 * kp;
        atomicAdd(&agg[(size_t)dstL[(eh * 2 + 0) * 32 + r] * 64 + o], CC[0][reg] + CC[2][reg]);
    }
#pragma unroll
    for (int reg = 0; reg < 16; reg++) {
        int r = (reg & 3) + 8 * (reg >> 2) + 4 * kp;
        atomicAdd(&agg[(size_t)dstL[(eh * 2 + 1) * 32 + r] * 64 + o], CC[1][reg] + CC[3][reg]);
    }
}

__global__ __launch_bounds__(512) void k_node(const float* __restrict__ agg,
                                              const float* __restrict__ deg,
                                              const float* __restrict__ rw,
                                              const float* __restrict__ rb,
                                              const float* __restrict__ lg,
                                              const float* __restrict__ lb,
                                              float* __restrict__ h,
                                              const int* __restrict__ batch,
                                              float* __restrict__ pooled,
                                              int last) {
    __shared__ __align__(16) NodeSh N;
    node_phase(N, agg, deg, rw, rb, lg, lb, h, batch, pooled, last);
}

__global__ __launch_bounds__(256) void k_head(const float* __restrict__ pooled,
                                              const int* __restrict__ batch,
                                              const float* __restrict__ pw1, const float* __restrict__ pb1,
                                              const float* __restrict__ pw2, const float* __restrict__ pb2,
                                              const float* __restrict__ pw3, const float* __restrict__ pb3,
                                              float* __restrict__ out) {
    __shared__ float cntL[32];
    __shared__ float ps[32][64];
    __shared__ float p1[32][64];
    __shared__ float p2[32][32];
    int t = threadIdx.x;
    if (t < 32) cntL[t] = 0.f;
    __syncthreads();
    {
        const int4* bp4 = (const int4*)(batch + t * 64);
        int cur = batch[t * 64];
        float c = 0.f;
        for (int q = 0; q < 16; q++) {
            int4 b4 = bp4[q];
            int bs[4] = { b4.x, b4.y, b4.z, b4.w };
#pragma unroll
            for (int e = 0; e < 4; e++) {
                if (bs[e] != cur) { atomicAdd(&cntL[cur], c); cur = bs[e]; c = 0.f; }
                c += 1.f;
            }
        }
        atomicAdd(&cntL[cur], c);
    }
    __syncthreads();
    for (int idx = t; idx < 2048; idx += 256) {
        int b = idx >> 6, j = idx & 63;
        ps[b][j] = pooled[idx] / fmaxf(cntL[b], 1.0f);
    }
    __syncthreads();
    for (int idx = t; idx < 2048; idx += 256) {
        int b = idx >> 6, j = idx & 63;
        float v = pb1[j];
#pragma unroll 8
        for (int i = 0; i < 64; i++) v += ps[b][i] * pw1[j * 64 + i];
        p1[b][j] = leaky(v);
    }
    __syncthreads();
    for (int idx = t; idx < 1024; idx += 256) {
        int b = idx >> 5, j = idx & 31;
        float v = pb2[j];
#pragma unroll 8
        for (int i = 0; i < 64; i++) v += p1[b][i] * pw2[j * 64 + i];
        p2[b][j] = leaky(v);
    }
    __syncthreads();
    if (t < 32) {
        float v = pb3[0];
#pragma unroll 8
        for (int i = 0; i < 32; i++) v += p2[t][i] * pw3[i];
        out[t] = v;
    }
}

// ----------------------------------------------------------------
extern "C" void kernel_launch(void* const* d_in, const int* in_sizes, int n_in,
                              void* d_out, int out_size, void* d_ws, size_t ws_size,
                              hipStream_t stream) {
    const float* x    = (const float*)d_in[0];
    const int*   eidx = (const int*)  d_in[1];
    const float* ea   = (const float*)d_in[2];
    const int*   bat  = (const int*)  d_in[3];
    const float* Win  = (const float*)d_in[4];
    const float* bin  = (const float*)d_in[5];
    const float* ew1  = (const float*)d_in[6];
    const float* eb1  = (const float*)d_in[7];
    const float* ew2  = (const float*)d_in[8];
    const float* eb2  = (const float*)d_in[9];
    const float* ew3  = (const float*)d_in[10];
    const float* eb3  = (const float*)d_in[11];
    const float* rw   = (const float*)d_in[12];
    const float* rb   = (const float*)d_in[13];
    const float* lg   = (const float*)d_in[14];
    const float* lb   = (const float*)d_in[15];
    const float* pw1  = (const float*)d_in[16];
    const float* pb1  = (const float*)d_in[17];
    const float* pw2  = (const float*)d_in[18];
    const float* pb2  = (const float*)d_in[19];
    const float* pw3  = (const float*)d_in[20];
    const float* pb3  = (const float*)d_in[21];
    float* out = (float*)d_out;

    float* ws     = (float*)d_ws;
    float* h      = ws;                          // 1048576
    float* agg    = ws + 1048576;                // 3 * 1048576
    float* deg    = ws + 4194304;                // 16384
    float* pooled = ws + 4210688;                // 2048 (+64 pad)
    f16*   Bp     = (f16*)(ws + 4212800);        // 3 * 266240 f16

    const int* srcp = eidx;
    const int* dstp = eidx + N_EDGES;

    // one memset covers agg[3] + deg + pooled (contiguous)
    (void)hipMemsetAsync(agg, 0, (size_t)3164224 * sizeof(float), stream);

    void* args[] = {
        (void*)&x, (void*)&ea, (void*)&srcp, (void*)&dstp, (void*)&bat,
        (void*)&Win, (void*)&bin,
        (void*)&ew1, (void*)&eb1, (void*)&ew2, (void*)&eb2,
        (void*)&ew3, (void*)&eb3,
        (void*)&rw, (void*)&rb, (void*)&lg, (void*)&lb,
        (void*)&pw1, (void*)&pb1, (void*)&pw2, (void*)&pb2,
        (void*)&pw3, (void*)&pb3,
        (void*)&h, (void*)&agg, (void*)&deg, (void*)&pooled, (void*)&Bp, (void*)&out
    };
    hipError_t err = hipLaunchCooperativeKernel((void*)k_fused, dim3(256), dim3(512),
                                                args, 0, stream);
    if (err != hipSuccess) {
        // fallback: r14's verified multi-kernel sequence (305.8 us)
        k_setup<<<4742, 256, 0, stream>>>(x, Win, bin, dstp, ew3, eb3, h, deg, Bp);
        for (int l = 0; l < NLAYERS; l++) {
            float* agg_l = agg + (size_t)l * N_NODES * H;
            k_msg <<<N_EDGES / 128, 256, 0, stream>>>(h, ea, ew1 + l * 320, eb1 + l * 64,
                                                      ew2 + l * 4096, eb2 + l * 64,
                                                      Bp + (size_t)l * 266240,
                                                      srcp, dstp, agg_l);
            k_node<<<N_NODES / 64, 512, 0, stream>>>(agg_l, deg, rw + l * 4096, rb + l * 64,
                                                     lg + l * 64, lb + l * 64, h,
                                                     bat, pooled, l == NLAYERS - 1 ? 1 : 0);
        }
        k_head<<<1, 256, 0, stream>>>(pooled, bat, pw1, pb1, pw2, pb2, pw3, pb3, out);
    }
}

// Round 16
// 330.661 us; speedup vs baseline: 1.5899x; 1.5899x over previous
//
#include <hip/hip_runtime.h>
#include <hip/hip_bf16.h>

#define N_NODES 16384
#define N_EDGES 65536
#define NB      32
#define H       64
#define NLAYERS 3
#define NEG     0.1f
#define LN_EPS  1e-5f

typedef _Float16 f16;
typedef _Float16 f16x2 __attribute__((ext_vector_type(2)));
typedef _Float16 f16x8 __attribute__((ext_vector_type(8)));
typedef __fp16   hf16x2 __attribute__((ext_vector_type(2)));
typedef float    f32x16 __attribute__((ext_vector_type(16)));

union F16x8 { f16x8 v; f16x2 p[4]; int4 i4; int2 i2[2]; };
union F16x2U { f16x2 h2; hf16x2 raw; unsigned int u; };
union F16U   { f16 h; unsigned short u; };

__device__ __forceinline__ f16x2 pkrtz(float a, float b) {
    F16x2U t; t.raw = __builtin_amdgcn_cvt_pkrtz(a, b); return t.h2;
}
__device__ __forceinline__ float leaky(float v) { return v > 0.f ? v : NEG * v; }

// ---------------------------------------------------------------- setup: inproj + degree + Bp prep (one dispatch)  [r14]
__global__ __launch_bounds__(256) void k_setup(const float* __restrict__ x,
                                               const float* __restrict__ Win,
                                               const float* __restrict__ bin,
                                               const int* __restrict__ dst,
                                               const float* __restrict__ ew3,
                                               const float* __restrict__ eb3,
                                               float* __restrict__ h,
                                               float* __restrict__ deg,
                                               f16* __restrict__ Bp) {
    int bid = blockIdx.x;
    if (bid < 4096) {                       // input projection
        int t = bid * 256 + threadIdx.x;
        int n = t >> 6, j = t & 63;
        const float* xr = x + n * 4;
        const float* wr = Win + j * 4;
        float v = bin[j] + xr[0] * wr[0] + xr[1] * wr[1] + xr[2] * wr[2] + xr[3] * wr[3];
        h[t] = leaky(v);
    } else if (bid < 4352) {                // degree atomics (deg pre-zeroed by memset)
        int e = (bid - 4096) * 256 + threadIdx.x;
        atomicAdd(&deg[dst[e]], 1.0f);
    } else {                                // Bp prep: 390 blocks = 1560 slots
        int tg    = (bid - 4352) * 256 + threadIdx.x;
        int lane  = tg & 63;
        int gslot = tg >> 6;
        int l     = gslot / 520;
        int slot  = gslot - l * 520;
        const float* ew3l = ew3 + (size_t)l * 262144;
        const float* eb3l = eb3 + (size_t)l * 4096;
        int i   = slot >> 3;
        int rem = slot & 7;
        int ks  = rem >> 1;
        int oq  = rem & 1;
        int o   = oq * 32 + (lane & 31);
        int k0  = ks * 16 + (lane >> 5) * 8;
        float v[8];
        if (i < 64) {
            const float* s = ew3l + ((size_t)(i * 64 + o)) * 64 + k0;
            float4 a = ((const float4*)s)[0];
            float4 b = ((const float4*)s)[1];
            v[0] = a.x; v[1] = a.y; v[2] = a.z; v[3] = a.w;
            v[4] = b.x; v[5] = b.y; v[6] = b.z; v[7] = b.w;
        } else {
#pragma unroll
            for (int j = 0; j < 8; j++) v[j] = eb3l[(k0 + j) * 64 + o];
        }
        union { int4 i4; f16 a[8]; } out;
#pragma unroll
        for (int j = 0; j < 8; j++) out.a[j] = (f16)v[j];
        *(int4*)(Bp + (size_t)l * 266240 + (size_t)slot * 512 + lane * 8) = out.i4;
    }
}

// ---------------------------------------------------------------- fused edge-MLP + bilinear MFMA GEMM + scatter  [r0/r14-proven, untouched]
#define HS_STRIDE 76   // u16; 152 B rows -> 2-way LDS banks (free)

__device__ __forceinline__ void loadB8(const f16* __restrict__ Bp, int c, int oq, int lane, F16x8* dstB) {
    const f16* base = Bp + (((size_t)(c * 16 + oq)) << 9) + lane * 8;
#pragma unroll
    for (int di = 0; di < 2; di++)
#pragma unroll
        for (int ks = 0; ks < 4; ks++)
            dstB[di * 4 + ks].i4 = *(const int4*)(base + ((di * 8 + ks * 2) << 9));
}
__device__ __forceinline__ void loadB4(const f16* __restrict__ Bp, int oq, int lane, F16x8* dstB) {
    const f16* base = Bp + (((size_t)(512 + oq)) << 9) + lane * 8;
#pragma unroll
    for (int ks = 0; ks < 4; ks++)
        dstB[ks].i4 = *(const int4*)(base + ((ks * 2) << 9));
}

__device__ __forceinline__ void msg_chunk2(int c, const F16x8* __restrict__ B,
                                           const unsigned short* hp0,
                                           const unsigned short* hp1,
                                           const f16x2 (*e2p)[4][4], f32x16* CC) {
    unsigned int rr0 = *(const unsigned int*)(hp0 + 2 * c);
    unsigned int rr1 = *(const unsigned int*)(hp1 + 2 * c);
    F16x2U h00, h01, h10, h11;
    h00.u = __builtin_amdgcn_perm(rr0, rr0, 0x01000100u);
    h10.u = __builtin_amdgcn_perm(rr0, rr0, 0x03020302u);
    h01.u = __builtin_amdgcn_perm(rr1, rr1, 0x01000100u);
    h11.u = __builtin_amdgcn_perm(rr1, rr1, 0x03020302u);
#pragma unroll
    for (int ks = 0; ks < 4; ks++) {
        F16x8 A00, A01, A10, A11;
#pragma unroll
        for (int r = 0; r < 4; r++) {
            A00.p[r] = h00.h2 * e2p[0][ks][r];
            A01.p[r] = h01.h2 * e2p[1][ks][r];
            A10.p[r] = h10.h2 * e2p[0][ks][r];
            A11.p[r] = h11.h2 * e2p[1][ks][r];
        }
        CC[0] = __builtin_amdgcn_mfma_f32_32x32x16_f16(A00.v, B[0 * 4 + ks].v, CC[0], 0, 0, 0);
        CC[1] = __builtin_amdgcn_mfma_f32_32x32x16_f16(A01.v, B[0 * 4 + ks].v, CC[1], 0, 0, 0);
        CC[2] = __builtin_amdgcn_mfma_f32_32x32x16_f16(A10.v, B[1 * 4 + ks].v, CC[2], 0, 0, 0);
        CC[3] = __builtin_amdgcn_mfma_f32_32x32x16_f16(A11.v, B[1 * 4 + ks].v, CC[3], 0, 0, 0);
    }
}

__global__ __launch_bounds__(256, 2) void k_msg(const float* __restrict__ h,
                                                const float* __restrict__ ea,
                                                const float* __restrict__ w1,
                                                const float* __restrict__ b1,
                                                const float* __restrict__ w2,
                                                const float* __restrict__ b2,
                                                const f16* __restrict__ Bp,
                                                const int* __restrict__ src,
                                                const int* __restrict__ dst,
                                                float* __restrict__ agg) {
    __shared__ __align__(16) unsigned short hsL[128 * HS_STRIDE];  // 19.5 KB
    __shared__ __align__(16) unsigned short e1L[128 * 72];         // 18 KB
    __shared__ __align__(16) unsigned short e2L[128 * 72];         // 18 KB
    __shared__ float eas[128 * 8];                                 // 4 KB
    __shared__ int dstL[128];

    const int t    = threadIdx.x;
    const int lane = t & 63;
    const int w    = t >> 6;
    const int eh   = w >> 1, oq = w & 1;
    const int m    = lane & 31;
    const int kp   = lane >> 5;
    const int eb   = blockIdx.x * 128;

    // ---- stage ea rows (5 -> pad 8)
    for (int idx = t; idx < 640; idx += 256) {
        int r = idx / 5, d = idx - r * 5;
        eas[r * 8 + d] = ea[(size_t)eb * 5 + idx];
    }
    // ---- stage h rows (gathered by src, fp32 -> f16): 2 threads per row
    {
        int e    = t >> 1;
        int half = t & 1;
        int nsrc = src[eb + e];
        const float4* hr = (const float4*)(h + (size_t)nsrc * 64 + half * 32);
        unsigned int* hrow = (unsigned int*)hsL + e * (HS_STRIDE / 2) + half * 16;
#pragma unroll
        for (int q = 0; q < 8; q++) {
            float4 v = hr[q];
            F16x2U p0, p1;
            p0.raw = __builtin_amdgcn_cvt_pkrtz(v.x, v.y);
            p1.raw = __builtin_amdgcn_cvt_pkrtz(v.z, v.w);
            hrow[q * 2 + 0] = p0.u;
            hrow[q * 2 + 1] = p1.u;
        }
        if (t < 128) dstL[t] = dst[eb + t];
    }
    __syncthreads();

    // ---- edge-MLP stage 1: e1 = leaky(ea @ w1^T + b1) -> e1L (f16)
    {
        int kk = t & 63;
        int eg = t >> 6;
        float w1r[5];
#pragma unroll
        for (int d = 0; d < 5; d++) w1r[d] = w1[kk * 5 + d];
        float b1r = b1[kk];
#pragma unroll 4
        for (int g = 0; g < 32; g++) {
            int row = eg * 32 + g;
            float4 a4 = *(const float4*)(eas + row * 8);
            float a5 = eas[row * 8 + 4];
            float v = b1r + a4.x * w1r[0] + a4.y * w1r[1] + a4.z * w1r[2] + a4.w * w1r[3] + a5 * w1r[4];
            F16U z; z.h = (f16)leaky(v);
            e1L[row * 72 + kk] = z.u;
        }
    }
    __syncthreads();

    // ---- edge-MLP stage 2 (MFMA): wave (eh, oq) -> tiles eh*2+tt, k_out half oq
    {
        F16x8 W2f[4];
#pragma unroll
        for (int ks = 0; ks < 4; ks++) {
            const float* s = w2 + (size_t)(oq * 32 + m) * 64 + ks * 16 + kp * 8;
            float4 a = ((const float4*)s)[0];
            float4 b = ((const float4*)s)[1];
            W2f[ks].p[0] = pkrtz(a.x, a.y);
            W2f[ks].p[1] = pkrtz(a.z, a.w);
            W2f[ks].p[2] = pkrtz(b.x, b.y);
            W2f[ks].p[3] = pkrtz(b.z, b.w);
        }
        float b2r = b2[oq * 32 + m];
#pragma unroll
        for (int tt = 0; tt < 2; tt++) {
            f32x16 C2 = {0,0,0,0,0,0,0,0,0,0,0,0,0,0,0,0};
#pragma unroll
            for (int ks = 0; ks < 4; ks++) {
                F16x8 A;
                A.i4 = *(const int4*)(e1L + (size_t)((eh * 2 + tt) * 32 + m) * 72 + ks * 16 + kp * 8);
                C2 = __builtin_amdgcn_mfma_f32_32x32x16_f16(A.v, W2f[ks].v, C2, 0, 0, 0);
            }
#pragma unroll
            for (int reg = 0; reg < 16; reg++) {
                int r = (reg & 3) + 8 * (reg >> 2) + 4 * kp;
                F16U z; z.h = (f16)leaky(C2[reg] + b2r);
                e2L[((eh * 2 + tt) * 32 + r) * 72 + oq * 32 + m] = z.u;
            }
        }
    }
    __syncthreads();

    // ---- read e2 A-operand pairs for this wave's 2 tiles (full k)
    f16x2 e2p[2][4][4];
#pragma unroll
    for (int tt = 0; tt < 2; tt++) {
#pragma unroll
        for (int ks = 0; ks < 4; ks++) {
            F16x8 q;
            q.i4 = *(const int4*)(e2L + (size_t)((eh * 2 + tt) * 32 + m) * 72 + ks * 16 + kp * 8);
            e2p[tt][ks][0] = q.p[0]; e2p[tt][ks][1] = q.p[1];
            e2p[tt][ks][2] = q.p[2]; e2p[tt][ks][3] = q.p[3];
        }
    }

    f32x16 CC[4];
#pragma unroll
    for (int q = 0; q < 4; q++)
#pragma unroll
        for (int r = 0; r < 16; r++) CC[q][r] = 0.f;

    const unsigned short* hp0 = hsL + ((eh * 2 + 0) * 32 + m) * HS_STRIDE;
    const unsigned short* hp1 = hsL + ((eh * 2 + 1) * 32 + m) * HS_STRIDE;

    // ---- STATIC double-buffered barrier-free K-loop
    F16x8 B0[8], B1[8];
    loadB8(Bp, 0, oq, lane, B0);
    loadB8(Bp, 1, oq, lane, B1);
    for (int it = 0; it < 15; it++) {
        int c = it * 2;
        msg_chunk2(c,     B0, hp0, hp1, e2p, CC);  loadB8(Bp, c + 2, oq, lane, B0);
        msg_chunk2(c + 1, B1, hp0, hp1, e2p, CC);  loadB8(Bp, c + 3, oq, lane, B1);
    }
    msg_chunk2(30, B0, hp0, hp1, e2p, CC);
    loadB4(Bp, oq, lane, B0);               // bias frags into B0[0..3]
    msg_chunk2(31, B1, hp0, hp1, e2p, CC);

    // ---- bias chunk: A = h itself (k plays the i role), B = eb3 frags
#pragma unroll
    for (int ks = 0; ks < 4; ks++) {
        int koff = (ks * 16 + kp * 8) * 2;
        const char* r0p = (const char*)hsL + (size_t)((eh * 2 + 0) * 32 + m) * (HS_STRIDE * 2) + koff;
        const char* r1p = (const char*)hsL + (size_t)((eh * 2 + 1) * 32 + m) * (HS_STRIDE * 2) + koff;
        F16x8 A0, A1;
        A0.i2[0] = *(const int2*)(r0p); A0.i2[1] = *(const int2*)(r0p + 8);
        A1.i2[0] = *(const int2*)(r1p); A1.i2[1] = *(const int2*)(r1p + 8);
        CC[0] = __builtin_amdgcn_mfma_f32_32x32x16_f16(A0.v, B0[ks].v, CC[0], 0, 0, 0);
        CC[1] = __builtin_amdgcn_mfma_f32_32x32x16_f16(A1.v, B0[ks].v, CC[1], 0, 0, 0);
    }

    // ---- merge i-parity chains, scatter
    int o = oq * 32 + m;
#pragma unroll
    for (int reg = 0; reg < 16; reg++) {
        int r = (reg & 3) + 8 * (reg >> 2) + 4 * kp;
        atomicAdd(&agg[(size_t)dstL[(eh * 2 + 0) * 32 + r] * 64 + o], CC[0][reg] + CC[2][reg]);
    }
#pragma unroll
    for (int reg = 0; reg < 16; reg++) {
        int r = (reg & 3) + 8 * (reg >> 2) + 4 * kp;
        atomicAdd(&agg[(size_t)dstL[(eh * 2 + 1) * 32 + r] * 64 + o], CC[1][reg] + CC[3][reg]);
    }
}

// ---------------------------------------------------------------- node update: r14's single-load-epoch body + last-block ticket head
struct NodeSh { unsigned short hA[64 * 72]; float outL[64][68]; };
struct HeadSh { float cntL[32]; float ps[32][64]; float p1[32][64]; float p2[32][32]; };
union NodeU { NodeSh n; HeadSh hd; };

__global__ __launch_bounds__(512) void k_node(const float* __restrict__ agg,
                                              const float* __restrict__ deg,
                                              const float* __restrict__ rw,
                                              const float* __restrict__ rb,
                                              const float* __restrict__ lg,
                                              const float* __restrict__ lb,
                                              float* __restrict__ h,
                                              const int* __restrict__ batch,
                                              float* __restrict__ pooled,
                                              int last,
                                              int* __restrict__ done,
                                              const float* __restrict__ pw1, const float* __restrict__ pb1,
                                              const float* __restrict__ pw2, const float* __restrict__ pb2,
                                              const float* __restrict__ pw3, const float* __restrict__ pb3,
                                              float* __restrict__ out) {
    __shared__ __align__(16) NodeU sh;
    __shared__ int isLastBlk;
    int t = threadIdx.x;                    // 0..511
    int nb = blockIdx.x * 64;
    int lane = t & 63, w = t >> 6;          // w 0..7
    int m = lane & 31, kp = lane >> 5;

    // ---- hoisted global loads: one epoch, issued before any barrier  [r14]
    int node = t >> 3, c0 = (t & 7) * 8;    // 8 threads/node, 8 channels each
    size_t gb = (size_t)(nb + node) * 64 + c0;
    float4 ag0 = *(const float4*)(agg + gb);
    float4 ag1 = *(const float4*)(agg + gb + 4);
    float4 hp0 = *(const float4*)(h + gb);
    float4 hp1 = *(const float4*)(h + gb + 4);
    float  vdeg = fmaxf(deg[nb + node], 1.0f);
    float4 gv0 = *(const float4*)(lg + c0);
    float4 gv1 = *(const float4*)(lg + c0 + 4);
    float4 bv0 = *(const float4*)(lb + c0);
    float4 bv1 = *(const float4*)(lb + c0 + 4);

    // ---- stage hA directly from hoisted h_prev regs (no extra load)
    {
        unsigned int* drow = (unsigned int*)sh.n.hA + node * 36 + c0 / 2;
        F16x2U p0, p1, p2, p3;
        p0.raw = __builtin_amdgcn_cvt_pkrtz(hp0.x, hp0.y);
        p1.raw = __builtin_amdgcn_cvt_pkrtz(hp0.z, hp0.w);
        p2.raw = __builtin_amdgcn_cvt_pkrtz(hp1.x, hp1.y);
        p3.raw = __builtin_amdgcn_cvt_pkrtz(hp1.z, hp1.w);
        drow[0] = p0.u; drow[1] = p1.u; drow[2] = p2.u; drow[3] = p3.u;
    }
    F16x8 Bf[4];
    if (t < 256) {
        int oq = w & 1;
#pragma unroll
        for (int ks = 0; ks < 4; ks++) {
            const float* s = rw + (size_t)(oq * 32 + m) * 64 + ks * 16 + kp * 8;
            float4 a = ((const float4*)s)[0];
            float4 b = ((const float4*)s)[1];
            Bf[ks].p[0] = pkrtz(a.x, a.y);
            Bf[ks].p[1] = pkrtz(a.z, a.w);
            Bf[ks].p[2] = pkrtz(b.x, b.y);
            Bf[ks].p[3] = pkrtz(b.z, b.w);
        }
    }
    __syncthreads();

    if (t < 256) {
        int nq = w >> 1, oq = w & 1;
        f32x16 C = {0,0,0,0,0,0,0,0,0,0,0,0,0,0,0,0};
#pragma unroll
        for (int ks = 0; ks < 4; ks++) {
            F16x8 A;
            A.i4 = *(const int4*)(sh.n.hA + (size_t)(nq * 32 + m) * 72 + ks * 16 + kp * 8);
            C = __builtin_amdgcn_mfma_f32_32x32x16_f16(A.v, Bf[ks].v, C, 0, 0, 0);
        }
        int o = oq * 32 + m;
        float rbv = rb[o];
#pragma unroll
        for (int reg = 0; reg < 16; reg++) {
            int r = (reg & 3) + 8 * (reg >> 2) + 4 * kp;
            sh.n.outL[nq * 32 + r][o] = C[reg] + rbv;   // agg added in LN phase
        }
    }
    __syncthreads();

    // ---- parallel LN: 8 threads/node, all operands already in registers  [r14]
    {
        float v[8];
        v[0] = sh.n.outL[node][c0 + 0] + ag0.x / vdeg;
        v[1] = sh.n.outL[node][c0 + 1] + ag0.y / vdeg;
        v[2] = sh.n.outL[node][c0 + 2] + ag0.z / vdeg;
        v[3] = sh.n.outL[node][c0 + 3] + ag0.w / vdeg;
        v[4] = sh.n.outL[node][c0 + 4] + ag1.x / vdeg;
        v[5] = sh.n.outL[node][c0 + 5] + ag1.y / vdeg;
        v[6] = sh.n.outL[node][c0 + 6] + ag1.z / vdeg;
        v[7] = sh.n.outL[node][c0 + 7] + ag1.w / vdeg;
        float s = 0.f;
#pragma unroll
        for (int i = 0; i < 8; i++) s += v[i];
        s += __shfl_xor(s, 1);
        s += __shfl_xor(s, 2);
        s += __shfl_xor(s, 4);
        float mu = s * (1.f / 64.f);
        float vs = 0.f;
#pragma unroll
        for (int i = 0; i < 8; i++) { float d = v[i] - mu; vs += d * d; }
        vs += __shfl_xor(vs, 1);
        vs += __shfl_xor(vs, 2);
        vs += __shfl_xor(vs, 4);
        float rs = rsqrtf(vs * (1.f / 64.f) + LN_EPS);
        float gfv[8] = { gv0.x, gv0.y, gv0.z, gv0.w, gv1.x, gv1.y, gv1.z, gv1.w };
        float bfv[8] = { bv0.x, bv0.y, bv0.z, bv0.w, bv1.x, bv1.y, bv1.z, bv1.w };
        float hfv[8] = { hp0.x, hp0.y, hp0.z, hp0.w, hp1.x, hp1.y, hp1.z, hp1.w };
        float hn[8];
#pragma unroll
        for (int i = 0; i < 8; i++) {
            float ov = (v[i] - mu) * rs * gfv[i] + bfv[i];
            hn[i] = leaky(ov) + hfv[i];
        }
        float4 hw0, hw1;
        hw0.x = hn[0]; hw0.y = hn[1]; hw0.z = hn[2]; hw0.w = hn[3];
        hw1.x = hn[4]; hw1.y = hn[5]; hw1.z = hn[6]; hw1.w = hn[7];
        *(float4*)(h + gb)     = hw0;
        *(float4*)(h + gb + 4) = hw1;
#pragma unroll
        for (int i = 0; i < 8; i++) sh.n.outL[node][c0 + i] = hn[i];
    }

    if (last) {
        __syncthreads();
        // ---- pooling: 8 waves x 8 nodes, shfl-free  [r14]
        {
            float accp = 0.f;
            int cur = batch[nb + w * 8];
            for (int q = 0; q < 8; q++) {
                int n = w * 8 + q;
                float hv = sh.n.outL[n][lane];
                int b = batch[nb + n];
                if (b != cur) { atomicAdd(&pooled[cur * 64 + lane], accp); accp = 0.f; cur = b; }
                accp += hv;
            }
            atomicAdd(&pooled[cur * 64 + lane], accp);
        }
        // ---- last-block ticket: winner runs prediction head  [r11/r13-verified mechanism]
        __threadfence();
        if (t == 0) isLastBlk = (atomicAdd(done, 1) == (int)gridDim.x - 1) ? 1 : 0;
        __syncthreads();                    // all outL reads done before union reuse
        if (!isLastBlk) return;

        // head body: 512-thread form (r10/r15-verified)
        HeadSh& Hh = sh.hd;
        if (t < 32) Hh.cntL[t] = 0.f;
        __syncthreads();
        {
            const int4* bp4 = (const int4*)(batch + t * 32);
            int cur = batch[t * 32];
            float c = 0.f;
            for (int q = 0; q < 8; q++) {
                int4 b4 = bp4[q];
                int bs[4] = { b4.x, b4.y, b4.z, b4.w };
#pragma unroll
                for (int e = 0; e < 4; e++) {
                    if (bs[e] != cur) { atomicAdd(&Hh.cntL[cur], c); cur = bs[e]; c = 0.f; }
                    c += 1.f;
                }
            }
            atomicAdd(&Hh.cntL[cur], c);
        }
        __syncthreads();
        for (int idx = t; idx < 2048; idx += 512) {
            int b = idx >> 6, j = idx & 63;
            float pv = atomicAdd(&pooled[idx], 0.0f);   // coherent (L2) read
            Hh.ps[b][j] = pv / fmaxf(Hh.cntL[b], 1.0f);
        }
        __syncthreads();
        for (int idx = t; idx < 2048; idx += 512) {
            int b = idx >> 6, j = idx & 63;
            float v = pb1[j];
#pragma unroll 8
            for (int i = 0; i < 64; i++) v += Hh.ps[b][i] * pw1[j * 64 + i];
            Hh.p1[b][j] = leaky(v);
        }
        __syncthreads();
        for (int idx = t; idx < 1024; idx += 512) {
            int b = idx >> 5, j = idx & 31;
            float v = pb2[j];
#pragma unroll 8
            for (int i = 0; i < 64; i++) v += Hh.p1[b][i] * pw2[j * 64 + i];
            Hh.p2[b][j] = leaky(v);
        }
        __syncthreads();
        if (t < 32) {
            float v = pb3[0];
#pragma unroll 8
            for (int i = 0; i < 32; i++) v += Hh.p2[t][i] * pw3[i];
            out[t] = v;
        }
    }
}

// ----------------------------------------------------------------
extern "C" void kernel_launch(void* const* d_in, const int* in_sizes, int n_in,
                              void* d_out, int out_size, void* d_ws, size_t ws_size,
                              hipStream_t stream) {
    const float* x    = (const float*)d_in[0];
    const int*   eidx = (const int*)  d_in[1];
    const float* ea   = (const float*)d_in[2];
    const int*   bat  = (const int*)  d_in[3];
    const float* Win  = (const float*)d_in[4];
    const float* bin  = (const float*)d_in[5];
    const float* ew1  = (const float*)d_in[6];
    const float* eb1  = (const float*)d_in[7];
    const float* ew2  = (const float*)d_in[8];
    const float* eb2  = (const float*)d_in[9];
    const float* ew3  = (const float*)d_in[10];
    const float* eb3  = (const float*)d_in[11];
    const float* rw   = (const float*)d_in[12];
    const float* rb   = (const float*)d_in[13];
    const float* lg   = (const float*)d_in[14];
    const float* lb   = (const float*)d_in[15];
    const float* pw1  = (const float*)d_in[16];
    const float* pb1  = (const float*)d_in[17];
    const float* pw2  = (const float*)d_in[18];
    const float* pb2  = (const float*)d_in[19];
    const float* pw3  = (const float*)d_in[20];
    const float* pb3  = (const float*)d_in[21];
    float* out = (float*)d_out;

    float* ws     = (float*)d_ws;
    float* h      = ws;                          // 1048576
    float* agg    = ws + 1048576;                // 3 * 1048576
    float* deg    = ws + 4194304;                // 16384
    float* pooled = ws + 4210688;                // 2048
    int*   done   = (int*)(ws + 4212736);        // pad region (memset-zeroed)
    f16*   Bp     = (f16*)(ws + 4212800);        // 3 * 266240 f16

    const int* srcp = eidx;
    const int* dstp = eidx + N_EDGES;

    // one memset covers agg[3] + deg + pooled + done pad (contiguous)
    (void)hipMemsetAsync(agg, 0, (size_t)3164224 * sizeof(float), stream);

    k_setup<<<4742, 256, 0, stream>>>(x, Win, bin, dstp, ew3, eb3, h, deg, Bp);

    for (int l = 0; l < NLAYERS; l++) {
        float* agg_l = agg + (size_t)l * N_NODES * H;
        k_msg <<<N_EDGES / 128, 256, 0, stream>>>(h, ea, ew1 + l * 320, eb1 + l * 64,
                                                  ew2 + l * 4096, eb2 + l * 64,
                                                  Bp + (size_t)l * 266240,
                                                  srcp, dstp, agg_l);
        k_node<<<N_NODES / 64, 512, 0, stream>>>(agg_l, deg, rw + l * 4096, rb + l * 64,
                                                 lg + l * 64, lb + l * 64, h,
                                                 bat, pooled, l == NLAYERS - 1 ? 1 : 0,
                                                 done, pw1, pb1, pw2, pb2, pw3, pb3, out);
    }
}

// Round 17
// 305.177 us; speedup vs baseline: 1.7227x; 1.0835x over previous
//
#include <hip/hip_runtime.h>
#include <hip/hip_bf16.h>

#define N_NODES 16384
#define N_EDGES 65536
#define NB      32
#define H       64
#define NLAYERS 3
#define NEG     0.1f
#define LN_EPS  1e-5f

typedef _Float16 f16;
typedef _Float16 f16x2 __attribute__((ext_vector_type(2)));
typedef _Float16 f16x8 __attribute__((ext_vector_type(8)));
typedef __fp16   hf16x2 __attribute__((ext_vector_type(2)));
typedef float    f32x16 __attribute__((ext_vector_type(16)));

union F16x8 { f16x8 v; f16x2 p[4]; int4 i4; int2 i2[2]; };
union F16x2U { f16x2 h2; hf16x2 raw; unsigned int u; };
union F16U   { f16 h; unsigned short u; };

__device__ __forceinline__ f16x2 pkrtz(float a, float b) {
    F16x2U t; t.raw = __builtin_amdgcn_cvt_pkrtz(a, b); return t.h2;
}
__device__ __forceinline__ float leaky(float v) { return v > 0.f ? v : NEG * v; }

// ---------------------------------------------------------------- setup: inproj + degree + Bp prep (one dispatch)
// Bp slot = i*8 + ks*2 + oq (i in [0,64]; i==64 = eb3 bias). layer stride 520 slots.
__global__ __launch_bounds__(256) void k_setup(const float* __restrict__ x,
                                               const float* __restrict__ Win,
                                               const float* __restrict__ bin,
                                               const int* __restrict__ dst,
                                               const float* __restrict__ ew3,
                                               const float* __restrict__ eb3,
                                               float* __restrict__ h,
                                               float* __restrict__ deg,
                                               f16* __restrict__ Bp) {
    int bid = blockIdx.x;
    if (bid < 4096) {                       // input projection
        int t = bid * 256 + threadIdx.x;
        int n = t >> 6, j = t & 63;
        const float* xr = x + n * 4;
        const float* wr = Win + j * 4;
        float v = bin[j] + xr[0] * wr[0] + xr[1] * wr[1] + xr[2] * wr[2] + xr[3] * wr[3];
        h[t] = leaky(v);
    } else if (bid < 4352) {                // degree atomics (deg pre-zeroed by memset)
        int e = (bid - 4096) * 256 + threadIdx.x;
        atomicAdd(&deg[dst[e]], 1.0f);
    } else {                                // Bp prep: 390 blocks = 1560 slots
        int tg    = (bid - 4352) * 256 + threadIdx.x;
        int lane  = tg & 63;
        int gslot = tg >> 6;
        int l     = gslot / 520;
        int slot  = gslot - l * 520;
        const float* ew3l = ew3 + (size_t)l * 262144;
        const float* eb3l = eb3 + (size_t)l * 4096;
        int i   = slot >> 3;
        int rem = slot & 7;
        int ks  = rem >> 1;
        int oq  = rem & 1;
        int o   = oq * 32 + (lane & 31);
        int k0  = ks * 16 + (lane >> 5) * 8;
        float v[8];
        if (i < 64) {
            const float* s = ew3l + ((size_t)(i * 64 + o)) * 64 + k0;
            float4 a = ((const float4*)s)[0];
            float4 b = ((const float4*)s)[1];
            v[0] = a.x; v[1] = a.y; v[2] = a.z; v[3] = a.w;
            v[4] = b.x; v[5] = b.y; v[6] = b.z; v[7] = b.w;
        } else {
#pragma unroll
            for (int j = 0; j < 8; j++) v[j] = eb3l[(k0 + j) * 64 + o];
        }
        union { int4 i4; f16 a[8]; } out;
#pragma unroll
        for (int j = 0; j < 8; j++) out.a[j] = (f16)v[j];
        *(int4*)(Bp + (size_t)l * 266240 + (size_t)slot * 512 + lane * 8) = out.i4;
    }
}

// ---------------------------------------------------------------- fused edge-MLP + bilinear MFMA GEMM + scatter  [r0-proven, untouched]
#define HS_STRIDE 76   // u16; 152 B rows -> 2-way LDS banks (free)

__device__ __forceinline__ void loadB8(const f16* __restrict__ Bp, int c, int oq, int lane, F16x8* dstB) {
    const f16* base = Bp + (((size_t)(c * 16 + oq)) << 9) + lane * 8;
#pragma unroll
    for (int di = 0; di < 2; di++)
#pragma unroll
        for (int ks = 0; ks < 4; ks++)
            dstB[di * 4 + ks].i4 = *(const int4*)(base + ((di * 8 + ks * 2) << 9));
}
__device__ __forceinline__ void loadB4(const f16* __restrict__ Bp, int oq, int lane, F16x8* dstB) {
    const f16* base = Bp + (((size_t)(512 + oq)) << 9) + lane * 8;
#pragma unroll
    for (int ks = 0; ks < 4; ks++)
        dstB[ks].i4 = *(const int4*)(base + ((ks * 2) << 9));
}

__device__ __forceinline__ void msg_chunk2(int c, const F16x8* __restrict__ B,
                                           const unsigned short* hp0,
                                           const unsigned short* hp1,
                                           const f16x2 (*e2p)[4][4], f32x16* CC) {
    unsigned int rr0 = *(const unsigned int*)(hp0 + 2 * c);
    unsigned int rr1 = *(const unsigned int*)(hp1 + 2 * c);
    F16x2U h00, h01, h10, h11;
    h00.u = __builtin_amdgcn_perm(rr0, rr0, 0x01000100u);
    h10.u = __builtin_amdgcn_perm(rr0, rr0, 0x03020302u);
    h01.u = __builtin_amdgcn_perm(rr1, rr1, 0x01000100u);
    h11.u = __builtin_amdgcn_perm(rr1, rr1, 0x03020302u);
#pragma unroll
    for (int ks = 0; ks < 4; ks++) {
        F16x8 A00, A01, A10, A11;
#pragma unroll
        for (int r = 0; r < 4; r++) {
            A00.p[r] = h00.h2 * e2p[0][ks][r];
            A01.p[r] = h01.h2 * e2p[1][ks][r];
            A10.p[r] = h10.h2 * e2p[0][ks][r];
            A11.p[r] = h11.h2 * e2p[1][ks][r];
        }
        CC[0] = __builtin_amdgcn_mfma_f32_32x32x16_f16(A00.v, B[0 * 4 + ks].v, CC[0], 0, 0, 0);
        CC[1] = __builtin_amdgcn_mfma_f32_32x32x16_f16(A01.v, B[0 * 4 + ks].v, CC[1], 0, 0, 0);
        CC[2] = __builtin_amdgcn_mfma_f32_32x32x16_f16(A10.v, B[1 * 4 + ks].v, CC[2], 0, 0, 0);
        CC[3] = __builtin_amdgcn_mfma_f32_32x32x16_f16(A11.v, B[1 * 4 + ks].v, CC[3], 0, 0, 0);
    }
}

__global__ __launch_bounds__(256, 2) void k_msg(const float* __restrict__ h,
                                                const float* __restrict__ ea,
                                                const float* __restrict__ w1,
                                                const float* __restrict__ b1,
                                                const float* __restrict__ w2,
                                                const float* __restrict__ b2,
                                                const f16* __restrict__ Bp,
                                                const int* __restrict__ src,
                                                const int* __restrict__ dst,
                                                float* __restrict__ agg) {
    __shared__ __align__(16) unsigned short hsL[128 * HS_STRIDE];  // 19.5 KB
    __shared__ __align__(16) unsigned short e1L[128 * 72];         // 18 KB
    __shared__ __align__(16) unsigned short e2L[128 * 72];         // 18 KB
    __shared__ float eas[128 * 8];                                 // 4 KB
    __shared__ int dstL[128];

    const int t    = threadIdx.x;
    const int lane = t & 63;
    const int w    = t >> 6;
    const int eh   = w >> 1, oq = w & 1;
    const int m    = lane & 31;
    const int kp   = lane >> 5;
    const int eb   = blockIdx.x * 128;

    // ---- stage ea rows (5 -> pad 8)
    for (int idx = t; idx < 640; idx += 256) {
        int r = idx / 5, d = idx - r * 5;
        eas[r * 8 + d] = ea[(size_t)eb * 5 + idx];
    }
    // ---- stage h rows (gathered by src, fp32 -> f16): 2 threads per row
    {
        int e    = t >> 1;
        int half = t & 1;
        int nsrc = src[eb + e];
        const float4* hr = (const float4*)(h + (size_t)nsrc * 64 + half * 32);
        unsigned int* hrow = (unsigned int*)hsL + e * (HS_STRIDE / 2) + half * 16;
#pragma unroll
        for (int q = 0; q < 8; q++) {
            float4 v = hr[q];
            F16x2U p0, p1;
            p0.raw = __builtin_amdgcn_cvt_pkrtz(v.x, v.y);
            p1.raw = __builtin_amdgcn_cvt_pkrtz(v.z, v.w);
            hrow[q * 2 + 0] = p0.u;
            hrow[q * 2 + 1] = p1.u;
        }
        if (t < 128) dstL[t] = dst[eb + t];
    }
    __syncthreads();

    // ---- edge-MLP stage 1: e1 = leaky(ea @ w1^T + b1) -> e1L (f16)
    {
        int kk = t & 63;
        int eg = t >> 6;
        float w1r[5];
#pragma unroll
        for (int d = 0; d < 5; d++) w1r[d] = w1[kk * 5 + d];
        float b1r = b1[kk];
#pragma unroll 4
        for (int g = 0; g < 32; g++) {
            int row = eg * 32 + g;
            float4 a4 = *(const float4*)(eas + row * 8);
            float a5 = eas[row * 8 + 4];
            float v = b1r + a4.x * w1r[0] + a4.y * w1r[1] + a4.z * w1r[2] + a4.w * w1r[3] + a5 * w1r[4];
            F16U z; z.h = (f16)leaky(v);
            e1L[row * 72 + kk] = z.u;
        }
    }
    __syncthreads();

    // ---- edge-MLP stage 2 (MFMA): wave (eh, oq) -> tiles eh*2+tt, k_out half oq
    {
        F16x8 W2f[4];
#pragma unroll
        for (int ks = 0; ks < 4; ks++) {
            const float* s = w2 + (size_t)(oq * 32 + m) * 64 + ks * 16 + kp * 8;
            float4 a = ((const float4*)s)[0];
            float4 b = ((const float4*)s)[1];
            W2f[ks].p[0] = pkrtz(a.x, a.y);
            W2f[ks].p[1] = pkrtz(a.z, a.w);
            W2f[ks].p[2] = pkrtz(b.x, b.y);
            W2f[ks].p[3] = pkrtz(b.z, b.w);
        }
        float b2r = b2[oq * 32 + m];
#pragma unroll
        for (int tt = 0; tt < 2; tt++) {
            f32x16 C2 = {0,0,0,0,0,0,0,0,0,0,0,0,0,0,0,0};
#pragma unroll
            for (int ks = 0; ks < 4; ks++) {
                F16x8 A;
                A.i4 = *(const int4*)(e1L + (size_t)((eh * 2 + tt) * 32 + m) * 72 + ks * 16 + kp * 8);
                C2 = __builtin_amdgcn_mfma_f32_32x32x16_f16(A.v, W2f[ks].v, C2, 0, 0, 0);
            }
#pragma unroll
            for (int reg = 0; reg < 16; reg++) {
                int r = (reg & 3) + 8 * (reg >> 2) + 4 * kp;
                F16U z; z.h = (f16)leaky(C2[reg] + b2r);
                e2L[((eh * 2 + tt) * 32 + r) * 72 + oq * 32 + m] = z.u;
            }
        }
    }
    __syncthreads();

    // ---- read e2 A-operand pairs for this wave's 2 tiles (full k)
    f16x2 e2p[2][4][4];
#pragma unroll
    for (int tt = 0; tt < 2; tt++) {
#pragma unroll
        for (int ks = 0; ks < 4; ks++) {
            F16x8 q;
            q.i4 = *(const int4*)(e2L + (size_t)((eh * 2 + tt) * 32 + m) * 72 + ks * 16 + kp * 8);
            e2p[tt][ks][0] = q.p[0]; e2p[tt][ks][1] = q.p[1];
            e2p[tt][ks][2] = q.p[2]; e2p[tt][ks][3] = q.p[3];
        }
    }

    f32x16 CC[4];
#pragma unroll
    for (int q = 0; q < 4; q++)
#pragma unroll
        for (int r = 0; r < 16; r++) CC[q][r] = 0.f;

    const unsigned short* hp0 = hsL + ((eh * 2 + 0) * 32 + m) * HS_STRIDE;
    const unsigned short* hp1 = hsL + ((eh * 2 + 1) * 32 + m) * HS_STRIDE;

    // ---- STATIC double-buffered barrier-free K-loop
    F16x8 B0[8], B1[8];
    loadB8(Bp, 0, oq, lane, B0);
    loadB8(Bp, 1, oq, lane, B1);
    for (int it = 0; it < 15; it++) {
        int c = it * 2;
        msg_chunk2(c,     B0, hp0, hp1, e2p, CC);  loadB8(Bp, c + 2, oq, lane, B0);
        msg_chunk2(c + 1, B1, hp0, hp1, e2p, CC);  loadB8(Bp, c + 3, oq, lane, B1);
    }
    msg_chunk2(30, B0, hp0, hp1, e2p, CC);
    loadB4(Bp, oq, lane, B0);               // bias frags into B0[0..3]
    msg_chunk2(31, B1, hp0, hp1, e2p, CC);

    // ---- bias chunk: A = h itself (k plays the i role), B = eb3 frags
#pragma unroll
    for (int ks = 0; ks < 4; ks++) {
        int koff = (ks * 16 + kp * 8) * 2;
        const char* r0p = (const char*)hsL + (size_t)((eh * 2 + 0) * 32 + m) * (HS_STRIDE * 2) + koff;
        const char* r1p = (const char*)hsL + (size_t)((eh * 2 + 1) * 32 + m) * (HS_STRIDE * 2) + koff;
        F16x8 A0, A1;
        A0.i2[0] = *(const int2*)(r0p); A0.i2[1] = *(const int2*)(r0p + 8);
        A1.i2[0] = *(const int2*)(r1p); A1.i2[1] = *(const int2*)(r1p + 8);
        CC[0] = __builtin_amdgcn_mfma_f32_32x32x16_f16(A0.v, B0[ks].v, CC[0], 0, 0, 0);
        CC[1] = __builtin_amdgcn_mfma_f32_32x32x16_f16(A1.v, B0[ks].v, CC[1], 0, 0, 0);
    }

    // ---- merge i-parity chains, scatter
    int o = oq * 32 + m;
#pragma unroll
    for (int reg = 0; reg < 16; reg++) {
        int r = (reg & 3) + 8 * (reg >> 2) + 4 * kp;
        atomicAdd(&agg[(size_t)dstL[(eh * 2 + 0) * 32 + r] * 64 + o], CC[0][reg] + CC[2][reg]);
    }
#pragma unroll
    for (int reg = 0; reg < 16; reg++) {
        int r = (reg & 3) + 8 * (reg >> 2) + 4 * kp;
        atomicAdd(&agg[(size_t)dstL[(eh * 2 + 1) * 32 + r] * 64 + o], CC[1][reg] + CC[3][reg]);
    }
}

// ---------------------------------------------------------------- node update: MFMA root GEMM + PARALLEL LN, single load-epoch  [r14]
// 512 threads (8 waves/CU), all global loads HOISTED to entry (agg, h_prev,
// deg, ln params) -> one load epoch instead of three. The hoisted h_prev
// registers double as the f16 staging source. GEMM = 4-wave path under t<256.
__global__ __launch_bounds__(512) void k_node(const float* __restrict__ agg,
                                              const float* __restrict__ deg,
                                              const float* __restrict__ rw,
                                              const float* __restrict__ rb,
                                              const float* __restrict__ lg,
                                              const float* __restrict__ lb,
                                              float* __restrict__ h,
                                              const int* __restrict__ batch,
                                              float* __restrict__ pooled,
                                              int last) {
    __shared__ __align__(16) unsigned short hA[64 * 72];
    __shared__ float outL[64][68];
    int t = threadIdx.x;                    // 0..511
    int nb = blockIdx.x * 64;
    int lane = t & 63, w = t >> 6;          // w 0..7
    int m = lane & 31, kp = lane >> 5;

    // ---- hoisted global loads: one epoch, issued before any barrier
    int node = t >> 3, c0 = (t & 7) * 8;    // 8 threads/node, 8 channels each
    size_t gb = (size_t)(nb + node) * 64 + c0;
    float4 ag0 = *(const float4*)(agg + gb);
    float4 ag1 = *(const float4*)(agg + gb + 4);
    float4 hp0 = *(const float4*)(h + gb);
    float4 hp1 = *(const float4*)(h + gb + 4);
    float  vdeg = fmaxf(deg[nb + node], 1.0f);
    float4 gv0 = *(const float4*)(lg + c0);
    float4 gv1 = *(const float4*)(lg + c0 + 4);
    float4 bv0 = *(const float4*)(lb + c0);
    float4 bv1 = *(const float4*)(lb + c0 + 4);

    // ---- stage hA directly from hoisted h_prev regs (no extra load)
    {
        unsigned int* drow = (unsigned int*)hA + node * 36 + c0 / 2;
        F16x2U p0, p1, p2, p3;
        p0.raw = __builtin_amdgcn_cvt_pkrtz(hp0.x, hp0.y);
        p1.raw = __builtin_amdgcn_cvt_pkrtz(hp0.z, hp0.w);
        p2.raw = __builtin_amdgcn_cvt_pkrtz(hp1.x, hp1.y);
        p3.raw = __builtin_amdgcn_cvt_pkrtz(hp1.z, hp1.w);
        drow[0] = p0.u; drow[1] = p1.u; drow[2] = p2.u; drow[3] = p3.u;
    }
    F16x8 Bf[4];
    if (t < 256) {
        int oq = w & 1;
#pragma unroll
        for (int ks = 0; ks < 4; ks++) {
            const float* s = rw + (size_t)(oq * 32 + m) * 64 + ks * 16 + kp * 8;
            float4 a = ((const float4*)s)[0];
            float4 b = ((const float4*)s)[1];
            Bf[ks].p[0] = pkrtz(a.x, a.y);
            Bf[ks].p[1] = pkrtz(a.z, a.w);
            Bf[ks].p[2] = pkrtz(b.x, b.y);
            Bf[ks].p[3] = pkrtz(b.z, b.w);
        }
    }
    __syncthreads();

    if (t < 256) {
        int nq = w >> 1, oq = w & 1;
        f32x16 C = {0,0,0,0,0,0,0,0,0,0,0,0,0,0,0,0};
#pragma unroll
        for (int ks = 0; ks < 4; ks++) {
            F16x8 A;
            A.i4 = *(const int4*)(hA + (size_t)(nq * 32 + m) * 72 + ks * 16 + kp * 8);
            C = __builtin_amdgcn_mfma_f32_32x32x16_f16(A.v, Bf[ks].v, C, 0, 0, 0);
        }
        int o = oq * 32 + m;
        float rbv = rb[o];
#pragma unroll
        for (int reg = 0; reg < 16; reg++) {
            int r = (reg & 3) + 8 * (reg >> 2) + 4 * kp;
            outL[nq * 32 + r][o] = C[reg] + rbv;   // agg added in LN phase (hoisted regs)
        }
    }
    __syncthreads();

    // ---- parallel LN: 8 threads/node, all operands already in registers
    {
        float v[8];
        v[0] = outL[node][c0 + 0] + ag0.x / vdeg;
        v[1] = outL[node][c0 + 1] + ag0.y / vdeg;
        v[2] = outL[node][c0 + 2] + ag0.z / vdeg;
        v[3] = outL[node][c0 + 3] + ag0.w / vdeg;
        v[4] = outL[node][c0 + 4] + ag1.x / vdeg;
        v[5] = outL[node][c0 + 5] + ag1.y / vdeg;
        v[6] = outL[node][c0 + 6] + ag1.z / vdeg;
        v[7] = outL[node][c0 + 7] + ag1.w / vdeg;
        float s = 0.f;
#pragma unroll
        for (int i = 0; i < 8; i++) s += v[i];
        s += __shfl_xor(s, 1);
        s += __shfl_xor(s, 2);
        s += __shfl_xor(s, 4);
        float mu = s * (1.f / 64.f);
        float vs = 0.f;
#pragma unroll
        for (int i = 0; i < 8; i++) { float d = v[i] - mu; vs += d * d; }
        vs += __shfl_xor(vs, 1);
        vs += __shfl_xor(vs, 2);
        vs += __shfl_xor(vs, 4);
        float rs = rsqrtf(vs * (1.f / 64.f) + LN_EPS);
        float gfv[8] = { gv0.x, gv0.y, gv0.z, gv0.w, gv1.x, gv1.y, gv1.z, gv1.w };
        float bfv[8] = { bv0.x, bv0.y, bv0.z, bv0.w, bv1.x, bv1.y, bv1.z, bv1.w };
        float hfv[8] = { hp0.x, hp0.y, hp0.z, hp0.w, hp1.x, hp1.y, hp1.z, hp1.w };
        float hn[8];
#pragma unroll
        for (int i = 0; i < 8; i++) {
            float ov = (v[i] - mu) * rs * gfv[i] + bfv[i];
            hn[i] = leaky(ov) + hfv[i];
        }
        float4 hw0, hw1;
        hw0.x = hn[0]; hw0.y = hn[1]; hw0.z = hn[2]; hw0.w = hn[3];
        hw1.x = hn[4]; hw1.y = hn[5]; hw1.z = hn[6]; hw1.w = hn[7];
        *(float4*)(h + gb)     = hw0;
        *(float4*)(h + gb + 4) = hw1;
#pragma unroll
        for (int i = 0; i < 8; i++) outL[node][c0 + i] = hn[i];
    }

    // ---- pooling (last layer only): 8 waves x 8 nodes, shfl-free
    if (last) {
        __syncthreads();
        float accp = 0.f;
        int cur = batch[nb + w * 8];
        for (int q = 0; q < 8; q++) {
            int n = w * 8 + q;
            float hv = outL[n][lane];
            int b = batch[nb + n];
            if (b != cur) { atomicAdd(&pooled[cur * 64 + lane], accp); accp = 0.f; cur = b; }
            accp += hv;
        }
        atomicAdd(&pooled[cur * 64 + lane], accp);
    }
}

// ---------------------------------------------------------------- prediction head (1 block; computes cnt from sorted batch)
__global__ __launch_bounds__(256) void k_head(const float* __restrict__ pooled,
                                              const int* __restrict__ batch,
                                              const float* __restrict__ pw1, const float* __restrict__ pb1,
                                              const float* __restrict__ pw2, const float* __restrict__ pb2,
                                              const float* __restrict__ pw3, const float* __restrict__ pb3,
                                              float* __restrict__ out) {
    __shared__ float cntL[32];
    __shared__ float ps[32][64];
    __shared__ float p1[32][64];
    __shared__ float p2[32][32];
    int t = threadIdx.x;
    if (t < 32) cntL[t] = 0.f;
    __syncthreads();
    {
        const int4* bp4 = (const int4*)(batch + t * 64);
        int cur = batch[t * 64];
        float c = 0.f;
        for (int q = 0; q < 16; q++) {
            int4 b4 = bp4[q];
            int bs[4] = { b4.x, b4.y, b4.z, b4.w };
#pragma unroll
            for (int e = 0; e < 4; e++) {
                if (bs[e] != cur) { atomicAdd(&cntL[cur], c); cur = bs[e]; c = 0.f; }
                c += 1.f;
            }
        }
        atomicAdd(&cntL[cur], c);
    }
    __syncthreads();
    for (int idx = t; idx < 2048; idx += 256) {
        int b = idx >> 6, j = idx & 63;
        ps[b][j] = pooled[idx] / fmaxf(cntL[b], 1.0f);
    }
    __syncthreads();
    for (int idx = t; idx < 2048; idx += 256) {
        int b = idx >> 6, j = idx & 63;
        float v = pb1[j];
#pragma unroll 8
        for (int i = 0; i < 64; i++) v += ps[b][i] * pw1[j * 64 + i];
        p1[b][j] = leaky(v);
    }
    __syncthreads();
    for (int idx = t; idx < 1024; idx += 256) {
        int b = idx >> 5, j = idx & 31;
        float v = pb2[j];
#pragma unroll 8
        for (int i = 0; i < 64; i++) v += p1[b][i] * pw2[j * 64 + i];
        p2[b][j] = leaky(v);
    }
    __syncthreads();
    if (t < 32) {
        float v = pb3[0];
#pragma unroll 8
        for (int i = 0; i < 32; i++) v += p2[t][i] * pw3[i];
        out[t] = v;
    }
}

// ----------------------------------------------------------------
extern "C" void kernel_launch(void* const* d_in, const int* in_sizes, int n_in,
                              void* d_out, int out_size, void* d_ws, size_t ws_size,
                              hipStream_t stream) {
    const float* x    = (const float*)d_in[0];
    const int*   eidx = (const int*)  d_in[1];
    const float* ea   = (const float*)d_in[2];
    const int*   bat  = (const int*)  d_in[3];
    const float* Win  = (const float*)d_in[4];
    const float* bin  = (const float*)d_in[5];
    const float* ew1  = (const float*)d_in[6];
    const float* eb1  = (const float*)d_in[7];
    const float* ew2  = (const float*)d_in[8];
    const float* eb2  = (const float*)d_in[9];
    const float* ew3  = (const float*)d_in[10];
    const float* eb3  = (const float*)d_in[11];
    const float* rw   = (const float*)d_in[12];
    const float* rb   = (const float*)d_in[13];
    const float* lg   = (const float*)d_in[14];
    const float* lb   = (const float*)d_in[15];
    const float* pw1  = (const float*)d_in[16];
    const float* pb1  = (const float*)d_in[17];
    const float* pw2  = (const float*)d_in[18];
    const float* pb2  = (const float*)d_in[19];
    const float* pw3  = (const float*)d_in[20];
    const float* pb3  = (const float*)d_in[21];
    float* out = (float*)d_out;

    float* ws     = (float*)d_ws;
    float* h      = ws;                          // 1048576
    float* agg    = ws + 1048576;                // 3 * 1048576
    float* deg    = ws + 4194304;                // 16384
    float* pooled = ws + 4210688;                // 2048 (+64 pad)
    f16*   Bp     = (f16*)(ws + 4212800);        // 3 * 266240 f16

    const int* srcp = eidx;
    const int* dstp = eidx + N_EDGES;

    // one memset covers agg[3] + deg + pooled (contiguous)
    (void)hipMemsetAsync(agg, 0, (size_t)3164224 * sizeof(float), stream);

    k_setup<<<4742, 256, 0, stream>>>(x, Win, bin, dstp, ew3, eb3, h, deg, Bp);

    for (int l = 0; l < NLAYERS; l++) {
        float* agg_l = agg + (size_t)l * N_NODES * H;
        k_msg <<<N_EDGES / 128, 256, 0, stream>>>(h, ea, ew1 + l * 320, eb1 + l * 64,
                                                  ew2 + l * 4096, eb2 + l * 64,
                                                  Bp + (size_t)l * 266240,
                                                  srcp, dstp, agg_l);
        k_node<<<N_NODES / 64, 512, 0, stream>>>(agg_l, deg, rw + l * 4096, rb + l * 64,
                                                 lg + l * 64, lb + l * 64, h,
                                                 bat, pooled, l == NLAYERS - 1 ? 1 : 0);
    }

    k_head<<<1, 256, 0, stream>>>(pooled, bat, pw1, pb1, pw2, pb2, pw3, pb3, out);
}